// Round 1
// baseline (574.560 us; speedup 1.0000x reference)
//
#include <hip/hip_runtime.h>
#include <hip/hip_bf16.h>
#include <math.h>
#include <stdint.h>

#define HH 768
#define TT 32
#define KK 832           // H + 2T
#define SS 2048
#define NSTEP 26         // KK / 32

typedef __attribute__((ext_vector_type(4))) float f32x4;
typedef __attribute__((ext_vector_type(8))) short bf16x8;
typedef __attribute__((ext_vector_type(4))) short bf16x4;

__device__ __forceinline__ short f2bf(float f) {
  union { float f; uint32_t u; } v; v.f = f;
  uint32_t u = v.u;
  return (short)((u + 0x7FFFu + ((u >> 16) & 1u)) >> 16);
}

// ws kernel: Bt[n][k] = bf16(lin_W[k][n]);  n in [0,768), k in [0,832)
__global__ void transpose_w_kernel(const float* __restrict__ lin_W,
                                   short* __restrict__ bt) {
  int i = blockIdx.x * 256 + threadIdx.x;
  if (i >= HH * KK) return;
  int n = i / KK;
  int k = i - n * KK;
  bt[i] = f2bf(lin_W[(size_t)k * HH + n]);
}

template <bool WS>
__global__ __launch_bounds__(512, 1) void ehr_kernel(
    const int* __restrict__ input_ids, const int* __restrict__ type_ids,
    const float* __restrict__ time_stamps, const float* __restrict__ ages,
    const int* __restrict__ visit_orders, const int* __restrict__ visit_segments,
    const float* __restrict__ W_word, const float* __restrict__ W_type,
    const float* __restrict__ W_order, const float* __restrict__ W_seg,
    const float* __restrict__ time_w, const float* __restrict__ time_phi,
    const float* __restrict__ age_w, const float* __restrict__ age_phi,
    const float* __restrict__ lin_W, const float* __restrict__ lin_b,
    const float* __restrict__ ln_g, const float* __restrict__ ln_beta,
    const short* __restrict__ bt_ws, float* __restrict__ out) {
  __shared__ short Bt[HH * 32];      // 48KB  [n][k] rows of 32 bf16 (64B)
  __shared__ short Atile[64 * 32];   // 4KB   [row][k]
  __shared__ float dtl[64], agel[64];
  __shared__ int idl[64], tyl[64], orl[64], sgl[64];
  __shared__ float tpar[128];        // tw | tphi | aw | aphi
  __shared__ float redS[4][64], redQ[4][64];

  const int tid = threadIdx.x;
  const int t0 = blockIdx.x * 64;

  if (tid < 128) {
    int j = tid & 31;
    float v;
    if (tid < 32) v = time_w[j];
    else if (tid < 64) v = time_phi[j];
    else if (tid < 96) v = age_w[j];
    else v = age_phi[j];
    tpar[tid] = v;
  }
  if (tid < 64) {
    int t = t0 + tid;
    int s = t & (SS - 1);
    float tsv = time_stamps[t];
    dtl[tid] = (s == 0) ? 0.f : (tsv - time_stamps[t - 1]);
    agel[tid] = ages[t];
    idl[tid] = input_ids[t];
    tyl[tid] = type_ids[t];
    orl[tid] = visit_orders[t];
    sgl[tid] = visit_segments[t];
  }
  __syncthreads();

  const int lane = tid & 63, wave = tid >> 6;
  const int wm = wave >> 2, wn = wave & 3;
  const int l15 = lane & 15, l4 = lane >> 4;

  // A-staging assignment: each thread stages 4 consecutive k for one row
  const int arow = tid >> 3, ac = tid & 7;
  const int myid = idl[arow];
  const float mydt = dtl[arow];
  const float myage = agel[arow];
  const float* wrow = W_word + (size_t)myid * HH;

  f32x4 acc[2][12];
#pragma unroll
  for (int mf = 0; mf < 2; ++mf)
#pragma unroll
    for (int nf = 0; nf < 12; ++nf) acc[mf][nf] = (f32x4)(0.0f);

  for (int st = 0; st < NSTEP; ++st) {
    const int k0 = st * 32;
    // ---- stage A tile: 64 rows x 32 k, bf16
    {
      int kg = k0 + ac * 4;
      bf16x4 w4;
      if (kg < HH) {
        const f32x4 v = *(const f32x4*)(wrow + kg);
        w4[0] = f2bf(v[0]); w4[1] = f2bf(v[1]);
        w4[2] = f2bf(v[2]); w4[3] = f2bf(v[3]);
      } else {
        int isAge = (kg >= HH + TT);
        int j = kg - (isAge ? (HH + TT) : HH);
        float x = isAge ? myage : mydt;
        int wof = isAge ? 64 : 0;
#pragma unroll
        for (int i = 0; i < 4; ++i)
          w4[i] = f2bf(sinf(x * tpar[wof + j + i] + tpar[wof + 32 + j + i]));
      }
      *(bf16x4*)(Atile + tid * 4) = w4;
    }
    // ---- stage B tile: 768 rows(n) x 32 k, bf16
    if (WS) {
#pragma unroll
      for (int p = 0; p < 6; ++p) {
        int chunk = p * 8 + wave;          // wave-uniform
        short* ldst = Bt + chunk * 512;    // 1KB per wave-call
        int n = chunk * 16 + (lane >> 2);
        int q = lane & 3;
        const short* src = bt_ws + (size_t)n * KK + k0 + q * 8;
        __builtin_amdgcn_global_load_lds(
            (const __attribute__((address_space(1))) unsigned int*)src,
            (__attribute__((address_space(3))) unsigned int*)ldst, 16, 0, 0);
      }
    } else {
#pragma unroll
      for (int i6 = 0; i6 < 6; ++i6) {
        int c = i6 * 512 + tid;
        int n = c >> 2, q = c & 3;
        int kb = k0 + q * 8;
        bf16x8 w8;
#pragma unroll
        for (int j = 0; j < 8; ++j) w8[j] = f2bf(lin_W[(size_t)(kb + j) * HH + n]);
        *(bf16x8*)(Bt + n * 32 + q * 8) = w8;
      }
    }
    __syncthreads();

    // ---- MFMA compute
    const bf16x8* Af = (const bf16x8*)Atile;
    const bf16x8* Bf = (const bf16x8*)Bt;
    bf16x8 a0 = Af[(wm * 32 + l15) * 4 + l4];
    bf16x8 a1 = Af[(wm * 32 + 16 + l15) * 4 + l4];
#pragma unroll
    for (int nf = 0; nf < 12; ++nf) {
      int n = wn * 192 + nf * 16 + l15;
      bf16x8 b = Bf[n * 4 + l4];
      acc[0][nf] = __builtin_amdgcn_mfma_f32_16x16x32_bf16(a0, b, acc[0][nf], 0, 0, 0);
      acc[1][nf] = __builtin_amdgcn_mfma_f32_16x16x32_bf16(a1, b, acc[1][nf], 0, 0, 0);
    }
    __syncthreads();
  }

  // ---- epilogue: tanh + embedding adds + LayerNorm
  float sp[2][4], sq[2][4];
#pragma unroll
  for (int mf = 0; mf < 2; ++mf)
#pragma unroll
    for (int r = 0; r < 4; ++r) { sp[mf][r] = 0.f; sq[mf][r] = 0.f; }

#pragma unroll
  for (int nf = 0; nf < 12; ++nf) {
    int n = wn * 192 + nf * 16 + l15;
    float bias = lin_b[n];
#pragma unroll
    for (int mf = 0; mf < 2; ++mf) {
#pragma unroll
      for (int r = 0; r < 4; ++r) {
        int row = wm * 32 + mf * 16 + l4 * 4 + r;
        float z = tanhf(acc[mf][nf][r] + bias);
        z += W_type[(size_t)tyl[row] * HH + n];
        z += W_order[(size_t)orl[row] * HH + n];
        z += W_seg[(size_t)sgl[row] * HH + n];
        acc[mf][nf][r] = z;
        sp[mf][r] += z;
        sq[mf][r] += z * z;
      }
    }
  }
  // reduce across the 16 columns held by l15 groups
#pragma unroll
  for (int m = 1; m < 16; m <<= 1) {
#pragma unroll
    for (int mf = 0; mf < 2; ++mf)
#pragma unroll
      for (int r = 0; r < 4; ++r) {
        sp[mf][r] += __shfl_xor(sp[mf][r], m, 64);
        sq[mf][r] += __shfl_xor(sq[mf][r], m, 64);
      }
  }
  if (l15 == 0) {
#pragma unroll
    for (int mf = 0; mf < 2; ++mf)
#pragma unroll
      for (int r = 0; r < 4; ++r) {
        int row = wm * 32 + mf * 16 + l4 * 4 + r;
        redS[wn][row] = sp[mf][r];
        redQ[wn][row] = sq[mf][r];
      }
  }
  __syncthreads();

  float mu[2][4], rs[2][4];
#pragma unroll
  for (int mf = 0; mf < 2; ++mf)
#pragma unroll
    for (int r = 0; r < 4; ++r) {
      int row = wm * 32 + mf * 16 + l4 * 4 + r;
      float s = redS[0][row] + redS[1][row] + redS[2][row] + redS[3][row];
      float q = redQ[0][row] + redQ[1][row] + redQ[2][row] + redQ[3][row];
      float m_ = s * (1.0f / 768.0f);
      float v_ = q * (1.0f / 768.0f) - m_ * m_;
      if (v_ < 0.f) v_ = 0.f;
      mu[mf][r] = m_;
      rs[mf][r] = rsqrtf(v_ + 1e-12f);
    }

#pragma unroll
  for (int nf = 0; nf < 12; ++nf) {
    int n = wn * 192 + nf * 16 + l15;
    float g = ln_g[n], be = ln_beta[n];
#pragma unroll
    for (int mf = 0; mf < 2; ++mf) {
#pragma unroll
      for (int r = 0; r < 4; ++r) {
        int row = wm * 32 + mf * 16 + l4 * 4 + r;
        out[(size_t)(t0 + row) * HH + n] =
            (acc[mf][nf][r] - mu[mf][r]) * rs[mf][r] * g + be;
      }
    }
  }
}

extern "C" void kernel_launch(void* const* d_in, const int* in_sizes, int n_in,
                              void* d_out, int out_size, void* d_ws, size_t ws_size,
                              hipStream_t stream) {
  const int* input_ids = (const int*)d_in[0];
  const int* type_ids = (const int*)d_in[1];
  const float* time_stamps = (const float*)d_in[2];
  const float* ages = (const float*)d_in[3];
  const int* visit_orders = (const int*)d_in[4];
  const int* visit_segments = (const int*)d_in[5];
  const float* W_word = (const float*)d_in[6];
  const float* W_type = (const float*)d_in[7];
  const float* W_order = (const float*)d_in[8];
  const float* W_seg = (const float*)d_in[9];
  const float* time_w = (const float*)d_in[10];
  const float* time_phi = (const float*)d_in[11];
  const float* age_w = (const float*)d_in[12];
  const float* age_phi = (const float*)d_in[13];
  const float* lin_W = (const float*)d_in[14];
  const float* lin_b = (const float*)d_in[15];
  const float* ln_g = (const float*)d_in[16];
  const float* ln_beta = (const float*)d_in[17];
  float* out = (float*)d_out;

  const size_t bt_bytes = (size_t)HH * KK * sizeof(short);
  const bool use_ws = (d_ws != nullptr) && (ws_size >= bt_bytes);

  if (use_ws) {
    short* bt = (short*)d_ws;
    transpose_w_kernel<<<dim3((HH * KK + 255) / 256), dim3(256), 0, stream>>>(lin_W, bt);
    ehr_kernel<true><<<dim3(1024), dim3(512), 0, stream>>>(
        input_ids, type_ids, time_stamps, ages, visit_orders, visit_segments,
        W_word, W_type, W_order, W_seg, time_w, time_phi, age_w, age_phi,
        lin_W, lin_b, ln_g, ln_beta, (const short*)bt, out);
  } else {
    ehr_kernel<false><<<dim3(1024), dim3(512), 0, stream>>>(
        input_ids, type_ids, time_stamps, ages, visit_orders, visit_segments,
        W_word, W_type, W_order, W_seg, time_w, time_phi, age_w, age_phi,
        lin_W, lin_b, ln_g, ln_beta, nullptr, out);
  }
}